// Round 7
// baseline (1294.752 us; speedup 1.0000x reference)
//
#include <hip/hip_runtime.h>

// GRU B=256,T=2000,I=23,H=128 (gate order r,z,n) + mean over T.
// 1 batch row per block, 256 blocks (1/CU). 512 threads = 8 waves, 2/SIMD.
//
// v9 vs v8: PIN BY VALUE.
// v8's pin(v2f&) took the ADDRESS of array elements -> SROA failed, the
// weight arrays lived in scratch, and the loop re-read ~480B/lane of
// weights from scratch(L2) every step (VGPR stayed 88, perf unchanged).
// Issue math: VALUBusy 68% @ ~1630cy/step => ~270 instr/lane/step vs ~135
// of real arithmetic -- half the stream was reload machinery.
// Fix: value-returning pinv() (no address ever taken) + volatile initial
// loads. Each weight element becomes the SSA result of an inline asm:
// not rematerializable, not re-loadable -> true VGPR residency (~200 VGPR,
// still 2 waves/SIMD under __launch_bounds__(512,2)).
// Everything else identical to v6 (LDS-only barrier, depth-2 x prefetch,
// exp2 prescale, packed v_pk_fma_f32 MACs).

#define Bb 256
#define Tt 2000
#define Ii 23
#define Hh 128

typedef float v2f __attribute__((ext_vector_type(2)));
typedef float v4f __attribute__((ext_vector_type(4)));

template <int N> struct ic { static constexpr int v = N; };

template <int ctrl>
__device__ __forceinline__ float dpp_movf(float v) {
    int r = __builtin_amdgcn_update_dpp(0, __builtin_bit_cast(int, v),
                                        ctrl, 0xf, 0xf, true);
    return __builtin_bit_cast(float, r);
}
__device__ __forceinline__ float swz_xor4(float v) {
    int r = __builtin_amdgcn_ds_swizzle(__builtin_bit_cast(int, v), 0x101F);
    return __builtin_bit_cast(float, r);
}
__device__ __forceinline__ void pk_fma(v2f& a, v2f b, v2f c) {
    asm("v_pk_fma_f32 %0, %1, %2, %0" : "+v"(a) : "v"(b), "v"(c));
}
__device__ __forceinline__ v2f pk_mul(v2f b, v2f c) {
    v2f d;
    asm("v_pk_mul_f32 %0, %1, %2" : "=v"(d) : "v"(b), "v"(c));
    return d;
}
__device__ __forceinline__ float fexp2(float x) {
#if __has_builtin(__builtin_amdgcn_exp2f)
    return __builtin_amdgcn_exp2f(x);
#else
    return exp2f(x);
#endif
}
// Value-returning register pin: no address taken, SSA-friendly; the result
// is an inline-asm value LLVM can neither rematerialize nor re-load.
__device__ __forceinline__ v2f pinv(v2f v) { asm("" : "+v"(v)); return v; }
__device__ __forceinline__ float pinf(float v) { asm("" : "+v"(v)); return v; }
// LDS-only barrier: does NOT drain vmcnt (x prefetch stays in flight).
__device__ __forceinline__ void bar_lds() {
    asm volatile("s_waitcnt lgkmcnt(0)\n\ts_barrier" ::: "memory");
}

// fold 8 accs over 16 kt-lanes, XOR-permuted: lane ends with the full sum
// of virtual slot p(kt) = ((kt&1)<<2)|(kt&2)|((kt>>2)&1).
__device__ __forceinline__ float fold16x8(const float a[8]) {
    float b0 = a[0] + dpp_movf<0xB1>(a[4]);   // xor1 (quad_perm [1,0,3,2])
    float b1 = a[1] + dpp_movf<0xB1>(a[5]);
    float b2 = a[2] + dpp_movf<0xB1>(a[6]);
    float b3 = a[3] + dpp_movf<0xB1>(a[7]);
    float c0 = b0 + dpp_movf<0x4E>(b2);       // xor2 (quad_perm [2,3,0,1])
    float c1 = b1 + dpp_movf<0x4E>(b3);
    float d  = c0 + swz_xor4(c1);             // xor4 (only DS hop)
    return d + dpp_movf<0x128>(d);            // xor8 (row_ror:8)
}
// fold 4 accs over 16 kt-lanes: lane ends with full sum of slot
// p2(kt) = (kt&2)|((kt>>2)&1).
__device__ __forceinline__ float fold16x4(const float a[4]) {
    float b0 = a[0] + dpp_movf<0xB1>(a[0]);
    float b1 = a[1] + dpp_movf<0xB1>(a[1]);
    float b2 = a[2] + dpp_movf<0xB1>(a[2]);
    float b3 = a[3] + dpp_movf<0xB1>(a[3]);
    float c0 = b0 + dpp_movf<0x4E>(b2);
    float c1 = b1 + dpp_movf<0x4E>(b3);
    float d  = c0 + swz_xor4(c1);
    return d + dpp_movf<0x128>(d);
}

__global__ __launch_bounds__(512, 2)
void gru_fused(const float* __restrict__ x,     // [B,T,I]
               const float* __restrict__ W_ih,  // [3H,I]
               const float* __restrict__ W_hh,  // [3H,H]
               const float* __restrict__ b_ih,  // [3H]
               const float* __restrict__ b_hh,  // [3H]
               float* __restrict__ out)         // [B,H]
{
    const int b   = blockIdx.x;
    const int tid = threadIdx.x;
    const int wid = tid >> 6;
    const int l   = tid & 63;
    const int kt  = l & 15;
    const int kb  = kt * 8;
    const int p   = ((kt & 1) << 2) | (kt & 2) | ((kt >> 2) & 1);
    const int p2  = (kt & 2) | ((kt >> 2) & 1);
    const int jbase = wid * 16 + ((l >> 4) << 2);

    __shared__ __align__(16) float h_db[2][16][12];  // double-buffered h

    const float L2E = 1.4426950408889634f;   // log2(e)
    const float K2  = 2.0f * L2E;

    // ---- recurrent weights as k-pairs (v2f); r/z prescaled by log2e,
    //      n prescaled by 2*log2e; volatile load + pin BY VALUE ----
    v2f wrz2[8][4];
    #pragma unroll
    for (int i = 0; i < 8; ++i) {
        const int u = i ^ p;
        const int g = (u >> 2) * Hh + jbase + (u & 3);
        const volatile v2f* wp =
            reinterpret_cast<const volatile v2f*>(W_hh + (size_t)g * Hh + kb);
        #pragma unroll
        for (int kk = 0; kk < 4; ++kk) {
            v2f w = wp[kk];
            w[0] *= L2E; w[1] *= L2E;
            wrz2[i][kk] = pinv(w);
        }
    }
    v2f wn2[4][4];
    #pragma unroll
    for (int q = 0; q < 4; ++q) {
        const int g = 2 * Hh + jbase + (q ^ p2);
        const volatile v2f* wp =
            reinterpret_cast<const volatile v2f*>(W_hh + (size_t)g * Hh + kb);
        #pragma unroll
        for (int kk = 0; kk < 4; ++kk) {
            v2f w = wp[kk];
            w[0] *= K2; w[1] *= K2;
            wn2[q][kk] = pinv(w);
        }
    }

    // ---- x-side weights: lane kt covers x idx xi0 (+1 if kt<7) ----
    const int xi0  = (kt < 7) ? kt * 2 : 7 + kt;      // 0..13 / 14..22
    const int xoff = (kt < 7) ? 1 : 0;                // dup-load if 0 (w=0)
    v2f wx2[8];
    #pragma unroll
    for (int i = 0; i < 8; ++i) {
        const int u = i ^ p;
        const int g = (u >> 2) * Hh + jbase + (u & 3);
        const volatile float* wp = W_ih + (size_t)g * Ii + xi0;
        v2f w;
        w[0] = wp[0] * L2E;
        w[1] = xoff ? wp[1] * L2E : 0.0f;
        wx2[i] = pinv(w);
    }
    v2f wxn2[4];
    #pragma unroll
    for (int q = 0; q < 4; ++q) {
        const int g = 2 * Hh + jbase + (q ^ p2);
        const volatile float* wp = W_ih + (size_t)g * Ii + xi0;
        v2f w;
        w[0] = wp[0] * K2;
        w[1] = xoff ? wp[1] * K2 : 0.0f;
        wxn2[q] = pinv(w);
    }

    // ---- per-lane biases (post-fold), prescaled, pinned by value ----
    const int gp = (p >> 2) * Hh + jbase + (p & 3);
    const float brz_l = pinf((b_ih[gp] + b_hh[gp]) * L2E);
    const int jn = jbase + p2;
    const float bhn_l = pinf(b_hh[2 * Hh + jn] * K2);
    const float bxn_l = pinf(b_ih[2 * Hh + jn] * K2);

    const float* xrow = x + (size_t)b * Tt * Ii;

    // ---- init ----
    if (tid < Hh) h_db[0][tid >> 3][tid & 7] = 0.0f;
    // depth-2 x prefetch: P0 serves even steps, P1 odd steps.
    float x0a = xrow[xi0],      x0b = xrow[xi0 + xoff];
    float x1a = xrow[Ii + xi0], x1b = xrow[Ii + xi0 + xoff];
    int xob = 2 * Ii + xi0;                 // element index of row step+2
    float h_reg = 0.0f, acc_mean = 0.0f;
    const bool writer = ((kt & 9) == 0);    // kt in {0,2,4,6} -> p in {0,2,1,3}
    const int  jw = jbase + p;
    bar_lds();

    auto body = [&](auto CUR, int s) {
        constexpr int cur = decltype(CUR)::v;
        const int step = s + cur;

        // ---- h tile: 8 floats as 2x b128, split into pairs ----
        const v4f hA = *reinterpret_cast<const v4f*>(&h_db[cur][kt][0]);
        const v4f hB = *reinterpret_cast<const v4f*>(&h_db[cur][kt][4]);
        v2f hp[4];
        hp[0] = __builtin_shufflevector(hA, hA, 0, 1);
        hp[1] = __builtin_shufflevector(hA, hA, 2, 3);
        hp[2] = __builtin_shufflevector(hB, hB, 0, 1);
        hp[3] = __builtin_shufflevector(hB, hB, 2, 3);

        // ---- packed recurrent MACs: 8 r/z + 4 n gates ----
        v2f acc[8], accn[4];
        #pragma unroll
        for (int i = 0; i < 8; ++i) acc[i] = pk_mul(wrz2[i][0], hp[0]);
        #pragma unroll
        for (int q = 0; q < 4; ++q) accn[q] = pk_mul(wn2[q][0], hp[0]);
        #pragma unroll
        for (int kk = 1; kk < 4; ++kk) {
            #pragma unroll
            for (int i = 0; i < 8; ++i) pk_fma(acc[i], wrz2[i][kk], hp[kk]);
            #pragma unroll
            for (int q = 0; q < 4; ++q) pk_fma(accn[q], wn2[q][kk], hp[kk]);
        }

        // ---- x-side: r/z folds into acc; n kept separate ----
        v2f xpv;
        if constexpr (cur == 0) { xpv[0] = x0a; xpv[1] = x0b; }
        else                    { xpv[0] = x1a; xpv[1] = x1b; }
        #pragma unroll
        for (int i = 0; i < 8; ++i) pk_fma(acc[i], wx2[i], xpv);
        float arz[8];
        #pragma unroll
        for (int i = 0; i < 8; ++i) arz[i] = acc[i][0] + acc[i][1];
        float an[4], axn[4];
        #pragma unroll
        for (int q = 0; q < 4; ++q) {
            an[q] = accn[q][0] + accn[q][1];
            v2f tq = pk_mul(wxn2[q], xpv);
            axn[q] = tq[0] + tq[1];
        }

        // ---- reload this parity's x pair for step+2 (vmcnt wait lands
        //      ~2 steps downstream; barrier does not drain it) ----
        if constexpr (cur == 0) { x0a = xrow[xob]; x0b = xrow[xob + xoff]; }
        else                    { x1a = xrow[xob]; x1b = xrow[xob + xoff]; }
        if (step + 3 < Tt) xob += Ii;

        // ---- folds (all in-wave) + biases ----
        const float rz_tot = fold16x8(arz) + brz_l;   // r/z pre-act at slot p
        const float ghn = fold16x4(an) + bhn_l;       // rec n-sum at slot p2
        const float gxn = fold16x4(axn) + bxn_l;      // x-side n-sum at slot p2

        // ---- in-register epilogue (valid on even-kt lanes) ----
        const float zin = dpp_movf<0xB1>(rz_tot);     // neighbor's z pre-act
        const float r  = __builtin_amdgcn_rcpf(1.0f + fexp2(-rz_tot));
        const float z  = __builtin_amdgcn_rcpf(1.0f + fexp2(-zin));
        const float npre = fmaf(r, ghn, gxn);         // pre-scaled by 2log2e
        const float tt2  = __builtin_amdgcn_rcpf(1.0f + fexp2(-npre));
        const float nn   = fmaf(2.0f, tt2, -1.0f);    // tanh
        const float h_new = fmaf(z, h_reg - nn, nn);
        h_reg = h_new;
        if (writer) {
            acc_mean += h_new;
            h_db[cur ^ 1][jw >> 3][jw & 7] = h_new;
        }
        bar_lds();   // LDS-only barrier, once per step
    };

    for (int s = 0; s < Tt; s += 2) {
        body(ic<0>{}, s);
        body(ic<1>{}, s);
    }

    if (writer) out[(size_t)b * Hh + jw] = acc_mean * (1.0f / Tt);
}

extern "C" void kernel_launch(void* const* d_in, const int* in_sizes, int n_in,
                              void* d_out, int out_size, void* d_ws, size_t ws_size,
                              hipStream_t stream) {
    const float* x    = (const float*)d_in[0];
    const float* W_ih = (const float*)d_in[1];
    const float* W_hh = (const float*)d_in[2];
    const float* b_ih = (const float*)d_in[3];
    const float* b_hh = (const float*)d_in[4];
    float* out = (float*)d_out;

    gru_fused<<<Bb, 512, 0, stream>>>(x, W_ih, W_hh, b_ih, b_hh, out);
}

// Round 8
// 1278.947 us; speedup vs baseline: 1.0124x; 1.0124x over previous
//
#include <hip/hip_runtime.h>

// GRU B=256,T=2000,I=23,H=128 (gate order r,z,n) + mean over T.
// 1 batch row per block, 256 blocks (1/CU). 512 threads = 8 waves, 2/SIMD.
//
// v10 vs v9: amdgpu_waves_per_eu(2,2).
// Counter forensics across v6/v8/v9: VGPR_Count pinned at 88 regardless of
// pin strategy, WRITE_SIZE == output only (no scratch), volatile loads
// can't re-execute -> the ~135 floats of persistent weight state live in
// AGPRs (gfx950 unified RF; rocprof VGPR_Count = arch VGPRs only), and
// every step pays ~120 v_accvgpr_read VALU ops to stream them back.
// Issue math: VALUBusy 67% @ ~1680cy/step = ~280 instr/lane/step vs ~140
// real arithmetic -- the gap is the AGPR traffic.
// __launch_bounds__(512,2) only sets MIN waves/EU; the allocator still
// targets 4 waves/SIMD (<=128 VGPR) and parks the overflow in AGPRs.
// amdgpu_waves_per_eu(2,2) sets min=max=2 -> 256 arch-VGPR budget, weights
// become true VGPR-resident operands. Grid is 1 block/CU (2 waves/SIMD)
// anyway, so capping occupancy at 2 costs nothing.
// Everything else identical to v9 (LDS-only barrier, depth-2 x prefetch,
// exp2 prescale, packed v_pk_fma_f32 MACs, volatile+pinv weight loads).

#define Bb 256
#define Tt 2000
#define Ii 23
#define Hh 128

typedef float v2f __attribute__((ext_vector_type(2)));
typedef float v4f __attribute__((ext_vector_type(4)));

template <int N> struct ic { static constexpr int v = N; };

template <int ctrl>
__device__ __forceinline__ float dpp_movf(float v) {
    int r = __builtin_amdgcn_update_dpp(0, __builtin_bit_cast(int, v),
                                        ctrl, 0xf, 0xf, true);
    return __builtin_bit_cast(float, r);
}
__device__ __forceinline__ float swz_xor4(float v) {
    int r = __builtin_amdgcn_ds_swizzle(__builtin_bit_cast(int, v), 0x101F);
    return __builtin_bit_cast(float, r);
}
__device__ __forceinline__ void pk_fma(v2f& a, v2f b, v2f c) {
    asm("v_pk_fma_f32 %0, %1, %2, %0" : "+v"(a) : "v"(b), "v"(c));
}
__device__ __forceinline__ v2f pk_mul(v2f b, v2f c) {
    v2f d;
    asm("v_pk_mul_f32 %0, %1, %2" : "=v"(d) : "v"(b), "v"(c));
    return d;
}
__device__ __forceinline__ float fexp2(float x) {
#if __has_builtin(__builtin_amdgcn_exp2f)
    return __builtin_amdgcn_exp2f(x);
#else
    return exp2f(x);
#endif
}
// Value-returning register pin: no address taken, SSA-friendly; the result
// is an inline-asm value LLVM can neither rematerialize nor re-load.
__device__ __forceinline__ v2f pinv(v2f v) { asm("" : "+v"(v)); return v; }
__device__ __forceinline__ float pinf(float v) { asm("" : "+v"(v)); return v; }
// LDS-only barrier: does NOT drain vmcnt (x prefetch stays in flight).
__device__ __forceinline__ void bar_lds() {
    asm volatile("s_waitcnt lgkmcnt(0)\n\ts_barrier" ::: "memory");
}

// fold 8 accs over 16 kt-lanes, XOR-permuted: lane ends with the full sum
// of virtual slot p(kt) = ((kt&1)<<2)|(kt&2)|((kt>>2)&1).
__device__ __forceinline__ float fold16x8(const float a[8]) {
    float b0 = a[0] + dpp_movf<0xB1>(a[4]);   // xor1 (quad_perm [1,0,3,2])
    float b1 = a[1] + dpp_movf<0xB1>(a[5]);
    float b2 = a[2] + dpp_movf<0xB1>(a[6]);
    float b3 = a[3] + dpp_movf<0xB1>(a[7]);
    float c0 = b0 + dpp_movf<0x4E>(b2);       // xor2 (quad_perm [2,3,0,1])
    float c1 = b1 + dpp_movf<0x4E>(b3);
    float d  = c0 + swz_xor4(c1);             // xor4 (only DS hop)
    return d + dpp_movf<0x128>(d);            // xor8 (row_ror:8)
}
// fold 4 accs over 16 kt-lanes: lane ends with full sum of slot
// p2(kt) = (kt&2)|((kt>>2)&1).
__device__ __forceinline__ float fold16x4(const float a[4]) {
    float b0 = a[0] + dpp_movf<0xB1>(a[0]);
    float b1 = a[1] + dpp_movf<0xB1>(a[1]);
    float b2 = a[2] + dpp_movf<0xB1>(a[2]);
    float b3 = a[3] + dpp_movf<0xB1>(a[3]);
    float c0 = b0 + dpp_movf<0x4E>(b2);
    float c1 = b1 + dpp_movf<0x4E>(b3);
    float d  = c0 + swz_xor4(c1);
    return d + dpp_movf<0x128>(d);
}

__global__
__attribute__((amdgpu_flat_work_group_size(512, 512)))
__attribute__((amdgpu_waves_per_eu(2, 2)))
void gru_fused(const float* __restrict__ x,     // [B,T,I]
               const float* __restrict__ W_ih,  // [3H,I]
               const float* __restrict__ W_hh,  // [3H,H]
               const float* __restrict__ b_ih,  // [3H]
               const float* __restrict__ b_hh,  // [3H]
               float* __restrict__ out)         // [B,H]
{
    const int b   = blockIdx.x;
    const int tid = threadIdx.x;
    const int wid = tid >> 6;
    const int l   = tid & 63;
    const int kt  = l & 15;
    const int kb  = kt * 8;
    const int p   = ((kt & 1) << 2) | (kt & 2) | ((kt >> 2) & 1);
    const int p2  = (kt & 2) | ((kt >> 2) & 1);
    const int jbase = wid * 16 + ((l >> 4) << 2);

    __shared__ __align__(16) float h_db[2][16][12];  // double-buffered h

    const float L2E = 1.4426950408889634f;   // log2(e)
    const float K2  = 2.0f * L2E;

    // ---- recurrent weights as k-pairs (v2f); r/z prescaled by log2e,
    //      n prescaled by 2*log2e; volatile load + pin BY VALUE ----
    v2f wrz2[8][4];
    #pragma unroll
    for (int i = 0; i < 8; ++i) {
        const int u = i ^ p;
        const int g = (u >> 2) * Hh + jbase + (u & 3);
        const volatile v2f* wp =
            reinterpret_cast<const volatile v2f*>(W_hh + (size_t)g * Hh + kb);
        #pragma unroll
        for (int kk = 0; kk < 4; ++kk) {
            v2f w = wp[kk];
            w[0] *= L2E; w[1] *= L2E;
            wrz2[i][kk] = pinv(w);
        }
    }
    v2f wn2[4][4];
    #pragma unroll
    for (int q = 0; q < 4; ++q) {
        const int g = 2 * Hh + jbase + (q ^ p2);
        const volatile v2f* wp =
            reinterpret_cast<const volatile v2f*>(W_hh + (size_t)g * Hh + kb);
        #pragma unroll
        for (int kk = 0; kk < 4; ++kk) {
            v2f w = wp[kk];
            w[0] *= K2; w[1] *= K2;
            wn2[q][kk] = pinv(w);
        }
    }

    // ---- x-side weights: lane kt covers x idx xi0 (+1 if kt<7) ----
    const int xi0  = (kt < 7) ? kt * 2 : 7 + kt;      // 0..13 / 14..22
    const int xoff = (kt < 7) ? 1 : 0;                // dup-load if 0 (w=0)
    v2f wx2[8];
    #pragma unroll
    for (int i = 0; i < 8; ++i) {
        const int u = i ^ p;
        const int g = (u >> 2) * Hh + jbase + (u & 3);
        const volatile float* wp = W_ih + (size_t)g * Ii + xi0;
        v2f w;
        w[0] = wp[0] * L2E;
        w[1] = xoff ? wp[1] * L2E : 0.0f;
        wx2[i] = pinv(w);
    }
    v2f wxn2[4];
    #pragma unroll
    for (int q = 0; q < 4; ++q) {
        const int g = 2 * Hh + jbase + (q ^ p2);
        const volatile float* wp = W_ih + (size_t)g * Ii + xi0;
        v2f w;
        w[0] = wp[0] * K2;
        w[1] = xoff ? wp[1] * K2 : 0.0f;
        wxn2[q] = pinv(w);
    }

    // ---- per-lane biases (post-fold), prescaled, pinned by value ----
    const int gp = (p >> 2) * Hh + jbase + (p & 3);
    const float brz_l = pinf((b_ih[gp] + b_hh[gp]) * L2E);
    const int jn = jbase + p2;
    const float bhn_l = pinf(b_hh[2 * Hh + jn] * K2);
    const float bxn_l = pinf(b_ih[2 * Hh + jn] * K2);

    const float* xrow = x + (size_t)b * Tt * Ii;

    // ---- init ----
    if (tid < Hh) h_db[0][tid >> 3][tid & 7] = 0.0f;
    // depth-2 x prefetch: P0 serves even steps, P1 odd steps.
    float x0a = xrow[xi0],      x0b = xrow[xi0 + xoff];
    float x1a = xrow[Ii + xi0], x1b = xrow[Ii + xi0 + xoff];
    int xob = 2 * Ii + xi0;                 // element index of row step+2
    float h_reg = 0.0f, acc_mean = 0.0f;
    const bool writer = ((kt & 9) == 0);    // kt in {0,2,4,6} -> p in {0,2,1,3}
    const int  jw = jbase + p;
    bar_lds();

    auto body = [&](auto CUR, int s) {
        constexpr int cur = decltype(CUR)::v;
        const int step = s + cur;

        // ---- h tile: 8 floats as 2x b128, split into pairs ----
        const v4f hA = *reinterpret_cast<const v4f*>(&h_db[cur][kt][0]);
        const v4f hB = *reinterpret_cast<const v4f*>(&h_db[cur][kt][4]);
        v2f hp[4];
        hp[0] = __builtin_shufflevector(hA, hA, 0, 1);
        hp[1] = __builtin_shufflevector(hA, hA, 2, 3);
        hp[2] = __builtin_shufflevector(hB, hB, 0, 1);
        hp[3] = __builtin_shufflevector(hB, hB, 2, 3);

        // ---- packed recurrent MACs: 8 r/z + 4 n gates ----
        v2f acc[8], accn[4];
        #pragma unroll
        for (int i = 0; i < 8; ++i) acc[i] = pk_mul(wrz2[i][0], hp[0]);
        #pragma unroll
        for (int q = 0; q < 4; ++q) accn[q] = pk_mul(wn2[q][0], hp[0]);
        #pragma unroll
        for (int kk = 1; kk < 4; ++kk) {
            #pragma unroll
            for (int i = 0; i < 8; ++i) pk_fma(acc[i], wrz2[i][kk], hp[kk]);
            #pragma unroll
            for (int q = 0; q < 4; ++q) pk_fma(accn[q], wn2[q][kk], hp[kk]);
        }

        // ---- x-side: r/z folds into acc; n kept separate ----
        v2f xpv;
        if constexpr (cur == 0) { xpv[0] = x0a; xpv[1] = x0b; }
        else                    { xpv[0] = x1a; xpv[1] = x1b; }
        #pragma unroll
        for (int i = 0; i < 8; ++i) pk_fma(acc[i], wx2[i], xpv);
        float arz[8];
        #pragma unroll
        for (int i = 0; i < 8; ++i) arz[i] = acc[i][0] + acc[i][1];
        float an[4], axn[4];
        #pragma unroll
        for (int q = 0; q < 4; ++q) {
            an[q] = accn[q][0] + accn[q][1];
            v2f tq = pk_mul(wxn2[q], xpv);
            axn[q] = tq[0] + tq[1];
        }

        // ---- reload this parity's x pair for step+2 (vmcnt wait lands
        //      ~2 steps downstream; barrier does not drain it) ----
        if constexpr (cur == 0) { x0a = xrow[xob]; x0b = xrow[xob + xoff]; }
        else                    { x1a = xrow[xob]; x1b = xrow[xob + xoff]; }
        if (step + 3 < Tt) xob += Ii;

        // ---- folds (all in-wave) + biases ----
        const float rz_tot = fold16x8(arz) + brz_l;   // r/z pre-act at slot p
        const float ghn = fold16x4(an) + bhn_l;       // rec n-sum at slot p2
        const float gxn = fold16x4(axn) + bxn_l;      // x-side n-sum at slot p2

        // ---- in-register epilogue (valid on even-kt lanes) ----
        const float zin = dpp_movf<0xB1>(rz_tot);     // neighbor's z pre-act
        const float r  = __builtin_amdgcn_rcpf(1.0f + fexp2(-rz_tot));
        const float z  = __builtin_amdgcn_rcpf(1.0f + fexp2(-zin));
        const float npre = fmaf(r, ghn, gxn);         // pre-scaled by 2log2e
        const float tt2  = __builtin_amdgcn_rcpf(1.0f + fexp2(-npre));
        const float nn   = fmaf(2.0f, tt2, -1.0f);    // tanh
        const float h_new = fmaf(z, h_reg - nn, nn);
        h_reg = h_new;
        if (writer) {
            acc_mean += h_new;
            h_db[cur ^ 1][jw >> 3][jw & 7] = h_new;
        }
        bar_lds();   // LDS-only barrier, once per step
    };

    for (int s = 0; s < Tt; s += 2) {
        body(ic<0>{}, s);
        body(ic<1>{}, s);
    }

    if (writer) out[(size_t)b * Hh + jw] = acc_mean * (1.0f / Tt);
}

extern "C" void kernel_launch(void* const* d_in, const int* in_sizes, int n_in,
                              void* d_out, int out_size, void* d_ws, size_t ws_size,
                              hipStream_t stream) {
    const float* x    = (const float*)d_in[0];
    const float* W_ih = (const float*)d_in[1];
    const float* W_hh = (const float*)d_in[2];
    const float* b_ih = (const float*)d_in[3];
    const float* b_hh = (const float*)d_in[4];
    float* out = (float*)d_out;

    gru_fused<<<Bb, 512, 0, stream>>>(x, W_ih, W_hh, b_ih, b_hh, out);
}

// Round 9
// 1020.392 us; speedup vs baseline: 1.2689x; 1.2534x over previous
//
#include <hip/hip_runtime.h>

// GRU B=256,T=2000,I=23,H=128 (gate order r,z,n) + mean over T.
// 1 batch row per block, 256 blocks (1/CU). 512 threads = 8 waves, 2/SIMD.
//
// v11: ROW-PER-LANE remap -- kill every DS hop and lane exchange in the
// per-step serial chain.
//   lane = (jj=l>>2, kt=l&3); lane owns row j = wid*16+jj and computes
//   r,z,n for it over k in [32kt, 32kt+32): 48 h-pk + 9 x-pk MACs.
//   k-fold = symmetric 2-level DPP quad butterfly (xor1+xor2, VALU pipe,
//   NO ds_swizzle -- v6 had 3 serial DS-swizzle hops on the critical path
//   of every step). After the fold all 4 quad lanes hold the complete
//   r/z/ghn/gxn sums -> epilogue fully lane-local (no zin exchange,
//   h_prev in-register, uniform exec; kt==0 lane writes h).
//   h LDS layout [2][4][36]: stride 144B between kt-chunks -> the 4
//   distinct addresses of a read hit disjoint banks (conflict-free),
//   16-way broadcast within kt groups.
// Keeps from v6: LDS-only barrier (vmcnt stays in flight), depth-2 parity
// x prefetch, exp2 prescale, packed v_pk_fma_f32 MACs.

#define Bb 256
#define Tt 2000
#define Ii 23
#define Hh 128

typedef float v2f __attribute__((ext_vector_type(2)));
typedef float v4f __attribute__((ext_vector_type(4)));

template <int N> struct ic { static constexpr int v = N; };

template <int ctrl>
__device__ __forceinline__ float dpp_movf(float v) {
    int r = __builtin_amdgcn_update_dpp(0, __builtin_bit_cast(int, v),
                                        ctrl, 0xf, 0xf, true);
    return __builtin_bit_cast(float, r);
}
__device__ __forceinline__ void pk_fma(v2f& a, v2f b, v2f c) {
    asm("v_pk_fma_f32 %0, %1, %2, %0" : "+v"(a) : "v"(b), "v"(c));
}
__device__ __forceinline__ v2f pk_mul(v2f b, v2f c) {
    v2f d;
    asm("v_pk_mul_f32 %0, %1, %2" : "=v"(d) : "v"(b), "v"(c));
    return d;
}
__device__ __forceinline__ float fexp2(float x) {
#if __has_builtin(__builtin_amdgcn_exp2f)
    return __builtin_amdgcn_exp2f(x);
#else
    return exp2f(x);
#endif
}
__device__ __forceinline__ v2f pinv(v2f v) { asm("" : "+v"(v)); return v; }
__device__ __forceinline__ float pinf(float v) { asm("" : "+v"(v)); return v; }
// LDS-only barrier: does NOT drain vmcnt (x prefetch stays in flight).
__device__ __forceinline__ void bar_lds() {
    asm volatile("s_waitcnt lgkmcnt(0)\n\ts_barrier" ::: "memory");
}
// Symmetric quad butterfly: every lane of each quad ends with the quad sum.
// Pure VALU (2x quad_perm DPP + 2 adds) -- no DS pipe involvement.
__device__ __forceinline__ float qfold(float c) {
    c += dpp_movf<0xB1>(c);   // xor1: quad_perm [1,0,3,2]
    c += dpp_movf<0x4E>(c);   // xor2: quad_perm [2,3,0,1]
    return c;
}

__global__ __launch_bounds__(512, 2)
void gru_fused(const float* __restrict__ x,     // [B,T,I]
               const float* __restrict__ W_ih,  // [3H,I]
               const float* __restrict__ W_hh,  // [3H,H]
               const float* __restrict__ b_ih,  // [3H]
               const float* __restrict__ b_hh,  // [3H]
               float* __restrict__ out)         // [B,H]
{
    const int b   = blockIdx.x;
    const int tid = threadIdx.x;
    const int wid = tid >> 6;
    const int l   = tid & 63;
    const int jj  = l >> 2;            // 0..15: row within wave
    const int kt  = l & 3;             // k-quarter
    const int j   = wid * 16 + jj;     // owned h row
    const int kb  = kt * 32;           // k range [kb, kb+32)

    // h double buffer, padded: chunk stride 36 floats (144B, 16B-aligned,
    // banks disjoint across the 4 kt chunks).
    __shared__ __align__(16) float h_db[2][4][36];

    const float L2E = 1.4426950408889634f;   // log2(e)
    const float K2  = 2.0f * L2E;

    // ---- recurrent weights: 16 v2f per gate over k [kb,kb+32) ----
    v2f wr[16], wz[16], wn[16];
    {
        const float* Wr = W_hh + (size_t)j * Hh + kb;
        const float* Wz = W_hh + (size_t)(Hh + j) * Hh + kb;
        const float* Wn = W_hh + (size_t)(2 * Hh + j) * Hh + kb;
        #pragma unroll
        for (int kk = 0; kk < 16; ++kk) {
            v2f a = *reinterpret_cast<const v2f*>(Wr + 2 * kk);
            a[0] *= L2E; a[1] *= L2E; wr[kk] = pinv(a);
            v2f c = *reinterpret_cast<const v2f*>(Wz + 2 * kk);
            c[0] *= L2E; c[1] *= L2E; wz[kk] = pinv(c);
            v2f d = *reinterpret_cast<const v2f*>(Wn + 2 * kk);
            d[0] *= K2;  d[1] *= K2;  wn[kk] = pinv(d);
        }
    }

    // ---- x-side: lane kt covers x[xi0 .. ) as 3 pairs ----
    // kt<3: pairs (xi0,xi0+1),(xi0+2,xi0+3),(xi0+4,xi0+5), xi0=6kt
    // kt=3: pairs (18,19),(20,21),(21,22) with pair2.lo weight = 0
    const int xi0 = (kt < 3) ? kt * 6 : 18;
    const int xo2 = (kt < 3) ? 4 : 3;          // element offset of pair 2
    v2f wxr[3], wxz[3], wxn[3];
    {
        const float* Xr = W_ih + (size_t)j * Ii;
        const float* Xz = W_ih + (size_t)(Hh + j) * Ii;
        const float* Xn = W_ih + (size_t)(2 * Hh + j) * Ii;
        #pragma unroll
        for (int m = 0; m < 3; ++m) {
            const int e0 = xi0 + ((m < 2) ? 2 * m : xo2);
            const float klo = (kt == 3 && m == 2) ? 0.0f : 1.0f;
            v2f a; a[0] = Xr[e0] * L2E * klo; a[1] = Xr[e0 + 1] * L2E;
            wxr[m] = pinv(a);
            v2f c; c[0] = Xz[e0] * L2E * klo; c[1] = Xz[e0 + 1] * L2E;
            wxz[m] = pinv(c);
            v2f d; d[0] = Xn[e0] * K2 * klo;  d[1] = Xn[e0 + 1] * K2;
            wxn[m] = pinv(d);
        }
    }

    // ---- biases (post-fold, per-row, prescaled) ----
    const float br  = pinf((b_ih[j] + b_hh[j]) * L2E);
    const float bz  = pinf((b_ih[Hh + j] + b_hh[Hh + j]) * L2E);
    const float bnh = pinf(b_hh[2 * Hh + j] * K2);
    const float bnx = pinf(b_ih[2 * Hh + j] * K2);

    const float* xrow = x + (size_t)b * Tt * Ii + xi0;  // lane-local x base

    // ---- init ----
    if (tid < Hh) h_db[0][tid >> 5][tid & 31] = 0.0f;
    // depth-2 x prefetch: A serves even steps, B odd steps. 6 scalars each.
    float xA[6], xB[6];
    {
        #pragma unroll
        for (int m = 0; m < 4; ++m) { xA[m] = xrow[m]; xB[m] = xrow[Ii + m]; }
        xA[4] = xrow[xo2];     xA[5] = xrow[xo2 + 1];
        xB[4] = xrow[Ii + xo2]; xB[5] = xrow[Ii + xo2 + 1];
    }
    int xob = 2 * Ii;                  // element offset of row step+2
    float h_prev = 0.0f, acc_mean = 0.0f;
    bar_lds();

    auto body = [&](auto CUR, int s) {
        constexpr int cur = decltype(CUR)::v;
        const int step = s + cur;

        // ---- x-side MACs first (register-only, fills DS-latency window) --
        v2f xp0, xp1, xp2;
        if constexpr (cur == 0) {
            xp0[0]=xA[0]; xp0[1]=xA[1]; xp1[0]=xA[2]; xp1[1]=xA[3];
            xp2[0]=xA[4]; xp2[1]=xA[5];
        } else {
            xp0[0]=xB[0]; xp0[1]=xB[1]; xp1[0]=xB[2]; xp1[1]=xB[3];
            xp2[0]=xB[4]; xp2[1]=xB[5];
        }
        v2f ar = pk_mul(wxr[0], xp0);
        pk_fma(ar, wxr[1], xp1); pk_fma(ar, wxr[2], xp2);
        v2f az = pk_mul(wxz[0], xp0);
        pk_fma(az, wxz[1], xp1); pk_fma(az, wxz[2], xp2);
        v2f ax = pk_mul(wxn[0], xp0);
        pk_fma(ax, wxn[1], xp1); pk_fma(ax, wxn[2], xp2);

        // ---- h-side MACs: 8 b128 broadcast chunks, 6 pk each ----
        v2f ah;
        #pragma unroll
        for (int c = 0; c < 8; ++c) {
            const v4f hc = *reinterpret_cast<const v4f*>(&h_db[cur][kt][4 * c]);
            const v2f hpA = __builtin_shufflevector(hc, hc, 0, 1);
            const v2f hpB = __builtin_shufflevector(hc, hc, 2, 3);
            pk_fma(ar, wr[2 * c], hpA); pk_fma(ar, wr[2 * c + 1], hpB);
            pk_fma(az, wz[2 * c], hpA); pk_fma(az, wz[2 * c + 1], hpB);
            if (c == 0) {
                ah = pk_mul(wn[0], hpA); pk_fma(ah, wn[1], hpB);
            } else {
                pk_fma(ah, wn[2 * c], hpA); pk_fma(ah, wn[2 * c + 1], hpB);
            }
        }

        // ---- reload this parity's x for step+2 (in flight across bars) --
        if constexpr (cur == 0) {
            #pragma unroll
            for (int m = 0; m < 4; ++m) xA[m] = xrow[xob + m];
            xA[4] = xrow[xob + xo2]; xA[5] = xrow[xob + xo2 + 1];
        } else {
            #pragma unroll
            for (int m = 0; m < 4; ++m) xB[m] = xrow[xob + m];
            xB[4] = xrow[xob + xo2]; xB[5] = xrow[xob + xo2 + 1];
        }
        if (step + 3 < Tt) xob += Ii;

        // ---- quad folds (pure DPP) + biases: all 4 lanes get full sums --
        const float r_s = qfold(ar[0] + ar[1]) + br;
        const float z_s = qfold(az[0] + az[1]) + bz;
        const float ghn = qfold(ah[0] + ah[1]) + bnh;
        const float gxn = qfold(ax[0] + ax[1]) + bnx;

        // ---- lane-local epilogue (uniform across the quad) ----
        const float r  = __builtin_amdgcn_rcpf(1.0f + fexp2(-r_s));
        const float z  = __builtin_amdgcn_rcpf(1.0f + fexp2(-z_s));
        const float npre = fmaf(r, ghn, gxn);          // scaled by 2*log2e
        const float tt2  = __builtin_amdgcn_rcpf(1.0f + fexp2(-npre));
        const float nn   = fmaf(2.0f, tt2, -1.0f);     // tanh
        const float h_new = fmaf(z, h_prev - nn, nn);
        h_prev = h_new;
        acc_mean += h_new;
        if (kt == 0) h_db[cur ^ 1][j >> 5][j & 31] = h_new;
        bar_lds();   // LDS-only barrier, once per step
    };

    for (int s = 0; s < Tt; s += 2) {
        body(ic<0>{}, s);
        body(ic<1>{}, s);
    }

    if (kt == 0) out[(size_t)b * Hh + j] = acc_mean * (1.0f / Tt);
}

extern "C" void kernel_launch(void* const* d_in, const int* in_sizes, int n_in,
                              void* d_out, int out_size, void* d_ws, size_t ws_size,
                              hipStream_t stream) {
    const float* x    = (const float*)d_in[0];
    const float* W_ih = (const float*)d_in[1];
    const float* W_hh = (const float*)d_in[2];
    const float* b_ih = (const float*)d_in[3];
    const float* b_hh = (const float*)d_in[4];
    float* out = (float*)d_out;

    gru_fused<<<Bb, 512, 0, stream>>>(x, W_ih, W_hh, b_ih, b_hh, out);
}